// Round 8
// baseline (1018.762 us; speedup 1.0000x reference)
//
#include <hip/hip_runtime.h>
#include <stdint.h>

// VisionBlock: LN1 -> QKV GEMM -> [RoPE fused into attn] -> MFMA windowed attn (W=64) -> proj+res -> LN2 -> GELU MLP + res
// bf16 MFMA 16x16x32, fp32 accumulate everywhere.
// GEMM: 128x(32*NWJ) tile, BK=64, global_load_lds w=16, XOR swizzle, XCD-grouped, 3 blk/CU.
// v8: attn staging rewritten with wide loads (uint4/uint2/float4 straight-line, ~3x fewer VMEM
//     instructions) + packed LDS writes; compute phases bit-identical to v7.

#define SEQ   16384
#define HID   1152
#define NH    16
#define HDIM  72
#define INTER 4304
#define INTERP 4352
#define QKVN  3456

using bf16x8 = __attribute__((ext_vector_type(8))) __bf16;
using f32x4  = __attribute__((ext_vector_type(4))) float;

__device__ __forceinline__ float bf2f(uint16_t u){ return __uint_as_float(((uint32_t)u)<<16); }
__device__ __forceinline__ uint16_t f2bf(float f){
  uint32_t u = __float_as_uint(f);
  u += 0x7fffu + ((u>>16)&1u);
  return (uint16_t)(u>>16);
}
__device__ __forceinline__ uint32_t pk2(uint16_t a, uint16_t b){ return (uint32_t)a | ((uint32_t)b<<16); }
// 0.5x(1+tanh(0.79788456(x+0.044715x^3))) == x*sigmoid(1.59576912(x+0.044715x^3))
__device__ __forceinline__ float gelu_fast(float x){
  const float z = 2.3022085f * x * (1.0f + 0.044715f*x*x);
  return x / (1.0f + exp2f(-z));
}
__device__ __forceinline__ void async_load16(const void* g, void* l){
  __builtin_amdgcn_global_load_lds((__attribute__((address_space(1))) void*)(void*)g,
                                   (__attribute__((address_space(3))) void*)l, 16, 0, 0);
}

// ---------------- merged transpose + cast fp32[R][C] -> bf16[Cp][Rp], zero-padded ----------------
__global__ void transpose_cast_all(const float* __restrict__ s0, uint16_t* __restrict__ d0,
                                   const float* __restrict__ s1, uint16_t* __restrict__ d1,
                                   const float* __restrict__ s2, uint16_t* __restrict__ d2,
                                   const float* __restrict__ s3, uint16_t* __restrict__ d3)
{
  __shared__ float tile[32][33];
  int b = blockIdx.x;
  const float* src; uint16_t* dst; int R, C, Rp, bx, by;
  if (b < 3888){        src = s0; dst = d0; R = 1152; C = 3456; Rp = 1152; bx = b % 108; by = b / 108; }
  else if (b < 5184){   b -= 3888; src = s1; dst = d1; R = 1152; C = 1152; Rp = 1152; bx = b % 36; by = b / 36; }
  else if (b < 10080){  b -= 5184; src = s2; dst = d2; R = 1152; C = 4304; Rp = 1152; bx = b % 136; by = b / 136; }
  else {                b -= 10080; src = s3; dst = d3; R = 4304; C = 1152; Rp = 4352; bx = b % 36; by = b / 36; }
  const int tx = threadIdx.x & 31, ty = threadIdx.x >> 5;
  const int c = bx*32 + tx;
  #pragma unroll
  for (int s = 0; s < 4; ++s){
    const int r = by*32 + ty + s*8;
    tile[ty + s*8][tx] = (r < R && c < C) ? src[(size_t)r*C + c] : 0.0f;
  }
  __syncthreads();
  #pragma unroll
  for (int s = 0; s < 4; ++s){
    const int oc = bx*32 + ty + s*8;     // output row  (N dim)
    const int orr = by*32 + tx;          // output col  (K dim)
    dst[(size_t)oc*Rp + orr] = f2bf(tile[tx][ty + s*8]);
  }
}

// ---------------- LayerNorm: fp32 in -> bf16 out, one wave per row (float2 vectorized) ----------------
__global__ void ln_kernel(const float* __restrict__ x, const float* __restrict__ w,
                          const float* __restrict__ b, uint16_t* __restrict__ out)
{
  const int wid = threadIdx.x >> 6, lane = threadIdx.x & 63;
  const int row = blockIdx.x*4 + wid;
  const float2* xr = (const float2*)(x + (size_t)row*HID);
  float2 v[9];
  float s = 0.f;
  #pragma unroll
  for (int t = 0; t < 9; ++t){ v[t] = xr[lane + t*64]; s += v[t].x + v[t].y; }
  #pragma unroll
  for (int m = 32; m; m >>= 1) s += __shfl_xor(s, m, 64);
  const float mean = s * (1.0f/HID);
  float q = 0.f;
  #pragma unroll
  for (int t = 0; t < 9; ++t){
    float dx = v[t].x-mean, dy = v[t].y-mean;
    q += dx*dx + dy*dy;
  }
  #pragma unroll
  for (int m = 32; m; m >>= 1) q += __shfl_xor(q, m, 64);
  const float rstd = rsqrtf(q*(1.0f/HID) + 1e-6f);
  const float2* w2 = (const float2*)w;
  const float2* b2 = (const float2*)b;
  uint32_t* orow = (uint32_t*)(out + (size_t)row*HID);
  #pragma unroll
  for (int t = 0; t < 9; ++t){
    const int j = lane + t*64;
    const float2 wv = w2[j], bv = b2[j];
    const float o0 = (v[t].x-mean)*rstd*wv.x + bv.x;
    const float o1 = (v[t].y-mean)*rstd*wv.y + bv.y;
    orow[j] = (uint32_t)f2bf(o0) | ((uint32_t)f2bf(o1)<<16);
  }
}

// ---------------- MFMA windowed attention with fused RoPE: one block per (window, head) ----------------
// Layouts identical to v7 (Qb[64][104] with P overlay, Kb[64][104], Vt[80][72]); staging now uses
// straight-line wide loads: per row 4 threads = (Q,K) x (lo d 0..15 | lo d 16..35) with paired
// hi(+36) halves, plus a 3/2/2/2 split of V's 9 uint4 chunks. Rope math bit-identical to v7.
__global__ __launch_bounds__(256,4) void attn_kernel(const uint16_t* __restrict__ qkv,
                                                     const float* __restrict__ cosb,
                                                     const float* __restrict__ sinb,
                                                     uint16_t* __restrict__ outb)
{
  __shared__ uint16_t Qb[64*104];   // Q, then P overlays cols 0..63
  __shared__ uint16_t Kb[64*104];
  __shared__ uint16_t Vt[80*72];
  const int tid = threadIdx.x;
  const int win = blockIdx.x >> 4, h = blockIdx.x & 15;
  const size_t base = (size_t)win*64*QKVN + h*HDIM;
  // ---- staging: RoPE(Q,K) -> bf16, V transposed ----
  {
    const int r = tid >> 2, q4 = tid & 3;
    const size_t rb = base + (size_t)r*QKVN;
    const int isK = q4 >> 1, half = q4 & 1;
    const size_t mb = rb + (size_t)(isK ? HID : 0);
    uint16_t* dst = isK ? &Kb[r*104] : &Qb[r*104];
    const float* crow = cosb + (size_t)(win*64 + r)*HDIM;
    const float* srow = sinb + (size_t)(win*64 + r)*HDIM;
    if (half == 0){
      // d pairs from elems [0..15], partners [36..51]
      const uint4 L0 = *(const uint4*)(qkv + mb + 0);     // elems 0..7
      const uint4 L1 = *(const uint4*)(qkv + mb + 8);     // elems 8..15
      const uint2 H0 = *(const uint2*)(qkv + mb + 36);    // elems 36..39
      const uint4 H1 = *(const uint4*)(qkv + mb + 40);    // elems 40..47
      const uint2 H2 = *(const uint2*)(qkv + mb + 48);    // elems 48..51
      const uint32_t lo32[8] = {L0.x,L0.y,L0.z,L0.w,L1.x,L1.y,L1.z,L1.w};
      const uint32_t hi32[8] = {H0.x,H0.y,H1.x,H1.y,H1.z,H1.w,H2.x,H2.y};
      const float4 cc[4] = { *(const float4*)(crow+0),  *(const float4*)(crow+4),
                             *(const float4*)(crow+8),  *(const float4*)(crow+12) };
      const float4 ssv[4] = { *(const float4*)(srow+0), *(const float4*)(srow+4),
                              *(const float4*)(srow+8), *(const float4*)(srow+12) };
      uint32_t olo[8], ohi[8];
      #pragma unroll
      for (int j = 0; j < 8; ++j){
        const float l0 = bf2f((uint16_t)lo32[j]), l1 = bf2f((uint16_t)(lo32[j]>>16));
        const float h0 = bf2f((uint16_t)hi32[j]), h1 = bf2f((uint16_t)(hi32[j]>>16));
        const float cA = (j&1) ? cc[j>>1].z  : cc[j>>1].x;
        const float cB = (j&1) ? cc[j>>1].w  : cc[j>>1].y;
        const float sA = (j&1) ? ssv[j>>1].z : ssv[j>>1].x;
        const float sB = (j&1) ? ssv[j>>1].w : ssv[j>>1].y;
        olo[j] = pk2(f2bf(l0*cA - h0*sA), f2bf(l1*cB - h1*sB));
        ohi[j] = pk2(f2bf(h0*cA + l0*sA), f2bf(h1*cB + l1*sB));
      }
      *(uint4*)&dst[0]  = make_uint4(olo[0],olo[1],olo[2],olo[3]);
      *(uint4*)&dst[8]  = make_uint4(olo[4],olo[5],olo[6],olo[7]);
      *(uint2*)&dst[36] = make_uint2(ohi[0],ohi[1]);
      *(uint2*)&dst[40] = make_uint2(ohi[2],ohi[3]);
      *(uint2*)&dst[44] = make_uint2(ohi[4],ohi[5]);
      *(uint2*)&dst[48] = make_uint2(ohi[6],ohi[7]);
      *(uint4*)&dst[72] = make_uint4(0,0,0,0);            // zero pad cols 72..87
      *(uint4*)&dst[80] = make_uint4(0,0,0,0);
    } else {
      // d pairs from elems [16..35], partners [52..71]
      const uint4 A0 = *(const uint4*)(qkv + mb + 16);    // elems 16..23
      const uint4 A1 = *(const uint4*)(qkv + mb + 24);    // elems 24..31
      const uint2 A2 = *(const uint2*)(qkv + mb + 32);    // elems 32..35
      const uint2 D0 = *(const uint2*)(qkv + mb + 52);    // elems 52..55
      const uint4 E0 = *(const uint4*)(qkv + mb + 56);    // elems 56..63
      const uint4 F0 = *(const uint4*)(qkv + mb + 64);    // elems 64..71
      const uint32_t lo32[10] = {A0.x,A0.y,A0.z,A0.w,A1.x,A1.y,A1.z,A1.w,A2.x,A2.y};
      const uint32_t hi32[10] = {D0.x,D0.y,E0.x,E0.y,E0.z,E0.w,F0.x,F0.y,F0.z,F0.w};
      const float4 cc[5] = { *(const float4*)(crow+16), *(const float4*)(crow+20),
                             *(const float4*)(crow+24), *(const float4*)(crow+28),
                             *(const float4*)(crow+32) };
      const float4 ssv[5] = { *(const float4*)(srow+16), *(const float4*)(srow+20),
                              *(const float4*)(srow+24), *(const float4*)(srow+28),
                              *(const float4*)(srow+32) };
      uint32_t olo[10], ohi[10];
      #pragma unroll
      for (int j = 0; j < 10; ++j){
        const float l0 = bf2f((uint16_t)lo32[j]), l1 = bf2f((uint16_t)(lo32[j]>>16));
        const float h0 = bf2f((uint16_t)hi32[j]), h1 = bf2f((uint16_t)(hi32[j]>>16));
        const float cA = (j&1) ? cc[j>>1].z  : cc[j>>1].x;
        const float cB = (j&1) ? cc[j>>1].w  : cc[j>>1].y;
        const float sA = (j&1) ? ssv[j>>1].z : ssv[j>>1].x;
        const float sB = (j&1) ? ssv[j>>1].w : ssv[j>>1].y;
        olo[j] = pk2(f2bf(l0*cA - h0*sA), f2bf(l1*cB - h1*sB));
        ohi[j] = pk2(f2bf(h0*cA + l0*sA), f2bf(h1*cB + l1*sB));
      }
      *(uint4*)&dst[16] = make_uint4(olo[0],olo[1],olo[2],olo[3]);
      *(uint4*)&dst[24] = make_uint4(olo[4],olo[5],olo[6],olo[7]);
      *(uint2*)&dst[32] = make_uint2(olo[8],olo[9]);
      *(uint2*)&dst[52] = make_uint2(ohi[0],ohi[1]);
      *(uint4*)&dst[56] = make_uint4(ohi[2],ohi[3],ohi[4],ohi[5]);
      *(uint4*)&dst[64] = make_uint4(ohi[6],ohi[7],ohi[8],ohi[9]);
      *(uint4*)&dst[88] = make_uint4(0,0,0,0);            // zero pad cols 88..95
    }
    // V: 9 uint4 chunks per row, split 3/2/2/2 over the 4 row-threads
    const size_t vb = rb + 2*HID;
    #pragma unroll
    for (int u = 0; u < 3; ++u){
      const int c = (u < 2) ? (q4 + u*4) : 8;
      if (u < 2 || q4 == 0){
        const uint4 v = *(const uint4*)(qkv + vb + c*8);
        const int db = c*8;
        Vt[(db+0)*72 + r] = (uint16_t)v.x;  Vt[(db+1)*72 + r] = (uint16_t)(v.x>>16);
        Vt[(db+2)*72 + r] = (uint16_t)v.y;  Vt[(db+3)*72 + r] = (uint16_t)(v.y>>16);
        Vt[(db+4)*72 + r] = (uint16_t)v.z;  Vt[(db+5)*72 + r] = (uint16_t)(v.z>>16);
        Vt[(db+6)*72 + r] = (uint16_t)v.w;  Vt[(db+7)*72 + r] = (uint16_t)(v.w>>16);
      }
    }
  }
  // zero Vt pad rows 72..79 (8 dims x 64 tokens = 256 uint32, one per thread)
  {
    const int d = 72 + (tid >> 5), t = (tid & 31)*2;
    *(uint32_t*)&Vt[d*72 + t] = 0;
  }
  __syncthreads();

  const int wv = tid >> 6, lane = tid & 63;
  const int fr = lane & 15, fq = lane >> 4;
  // ---- QK^T: scores strip rows wv*16..+15, cols 0..63 ----
  f32x4 sacc[4] = {};
  __builtin_amdgcn_s_setprio(1);
  #pragma unroll
  for (int ks = 0; ks < 3; ++ks){
    const bf16x8 aq = *(const bf16x8*)&Qb[(wv*16 + fr)*104 + ks*32 + fq*8];
    #pragma unroll
    for (int j = 0; j < 4; ++j){
      const bf16x8 bk = *(const bf16x8*)&Kb[(j*16 + fr)*104 + ks*32 + fq*8];
      sacc[j] = __builtin_amdgcn_mfma_f32_16x16x32_bf16(aq, bk, sacc[j], 0, 0, 0);
    }
  }
  __builtin_amdgcn_s_setprio(0);
  // ---- softmax on C/D layout; write P (bf16) into Qb cols 0..63 (own strip only) ----
  const float scale = 0.11785113019775793f;   // 72^-0.5
  #pragma unroll
  for (int r = 0; r < 4; ++r){
    float a0 = sacc[0][r]*scale, a1 = sacc[1][r]*scale, a2 = sacc[2][r]*scale, a3 = sacc[3][r]*scale;
    float m = fmaxf(fmaxf(a0,a1), fmaxf(a2,a3));
    m = fmaxf(m, __shfl_xor(m, 1, 16));
    m = fmaxf(m, __shfl_xor(m, 2, 16));
    m = fmaxf(m, __shfl_xor(m, 4, 16));
    m = fmaxf(m, __shfl_xor(m, 8, 16));
    float e0 = __expf(a0-m), e1 = __expf(a1-m), e2 = __expf(a2-m), e3 = __expf(a3-m);
    float sm = e0+e1+e2+e3;
    sm += __shfl_xor(sm, 1, 16);
    sm += __shfl_xor(sm, 2, 16);
    sm += __shfl_xor(sm, 4, 16);
    sm += __shfl_xor(sm, 8, 16);
    const float inv = 1.0f/sm;
    const int prow = wv*16 + fq*4 + r;
    Qb[prow*104 +  0 + fr] = f2bf(e0*inv);
    Qb[prow*104 + 16 + fr] = f2bf(e1*inv);
    Qb[prow*104 + 32 + fr] = f2bf(e2*inv);
    Qb[prow*104 + 48 + fr] = f2bf(e3*inv);
  }
  // P rows wv*16..+15 are written and read by wave wv only -> no barrier needed.
  // ---- PV: out strip rows wv*16..+15, dims 0..71 (5 n-tiles, last half-padded) ----
  f32x4 oacc[5] = {};
  __builtin_amdgcn_s_setprio(1);
  #pragma unroll
  for (int k2 = 0; k2 < 2; ++k2){
    const bf16x8 ap = *(const bf16x8*)&Qb[(wv*16 + fr)*104 + k2*32 + fq*8];
    #pragma unroll
    for (int j = 0; j < 5; ++j){
      const bf16x8 bv = *(const bf16x8*)&Vt[(j*16 + fr)*72 + k2*32 + fq*8];
      oacc[j] = __builtin_amdgcn_mfma_f32_16x16x32_bf16(ap, bv, oacc[j], 0, 0, 0);
    }
  }
  __builtin_amdgcn_s_setprio(0);
  // ---- store: C/D layout col=dim, row=token ----
  #pragma unroll
  for (int j = 0; j < 5; ++j){
    const int d = j*16 + fr;
    if (d < HDIM){
      #pragma unroll
      for (int r = 0; r < 4; ++r){
        const int token = win*64 + wv*16 + fq*4 + r;
        outb[(size_t)token*HID + h*HDIM + d] = f2bf(oacc[j][r]);
      }
    }
  }
}

// ---------------- bf16 GEMM: C[M][N] = A[M][K] @ Bt[N][K]^T ----------------
// 128 x (32*NWJ) tile, BK=64, 1D grid (NB*MB, multiple of 8), XCD-grouped tiles.
// XOR swizzle: physical 8-elem slot k holds logical chunk k ^ ((row>>1)&3) (0 conflicts measured).
// NWJ=4: 128-wide n-tile; NWJ=3: 96-wide (integral rounds at 3 blk/CU for qkv/proj/fc2).
// EPI: 0 = bf16(bias), 1 = bf16(gelu(bias)), 2 = f32(bias + residual)
template<int EPI, int NWJ>
__global__ __launch_bounds__(256,3) void gemm_bt(
    const uint16_t* __restrict__ A, const uint16_t* __restrict__ Bt,
    const float* __restrict__ bias, int Nb,
    const float* res, void* outp, int N, int K, int NB)
{
  __shared__ uint16_t sA[128*64];
  __shared__ uint16_t sB[32*NWJ*64];
  const int tid = threadIdx.x, wid = tid >> 6, lane = tid & 63;
  const int per  = gridDim.x >> 3;
  const int tile = (blockIdx.x & 7)*per + (blockIdx.x >> 3);
  const int mb   = tile / NB;
  const int mBase = mb*128, nBase = (tile - mb*NB)*(32*NWJ);
  const int wm = wid >> 1, wn = wid & 1;
  const int sr = lane >> 2;
  const int sk = lane & 3;
  const int gk = sk ^ ((sr >> 1) & 3);
  const int rr = lane & 15;
  const int rq = lane >> 4;
  const int rp = rq ^ ((rr >> 1) & 3);
  f32x4 acc[4][NWJ] = {};

  for (int k0 = 0; k0 < K; k0 += 64){
    __syncthreads();
    #pragma unroll
    for (int j = 0; j < 4; ++j){
      const int c  = wid*4 + j;
      const int rc = c >> 1, h = c & 1;
      const size_t gcol = (size_t)(k0 + h*32 + gk*8);
      async_load16(A + (size_t)(mBase + rc*16 + sr)*K + gcol, &sA[c*512]);
    }
    #pragma unroll
    for (int j = 0; j < NWJ; ++j){
      const int c  = wid*NWJ + j;
      const int rc = c >> 1, h = c & 1;
      const size_t gcol = (size_t)(k0 + h*32 + gk*8);
      async_load16(Bt + (size_t)(nBase + rc*16 + sr)*K + gcol, &sB[c*512]);
    }
    __syncthreads();
    #pragma unroll
    for (int h = 0; h < 2; ++h){
      bf16x8 af[4], bfr[NWJ];
      #pragma unroll
      for (int i = 0; i < 4; ++i)
        af[i] = *(const bf16x8*)&sA[((wm*4 + i)*2 + h)*512 + rr*32 + rp*8];
      #pragma unroll
      for (int j = 0; j < NWJ; ++j)
        bfr[j] = *(const bf16x8*)&sB[((wn*NWJ + j)*2 + h)*512 + rr*32 + rp*8];
      #pragma unroll
      for (int i = 0; i < 4; ++i)
        #pragma unroll
        for (int j = 0; j < NWJ; ++j)
          acc[i][j] = __builtin_amdgcn_mfma_f32_16x16x32_bf16(af[i], bfr[j], acc[i][j], 0, 0, 0);
    }
  }

  const int rqd = (lane>>4)*4, cl = lane & 15;
  #pragma unroll
  for (int i = 0; i < 4; ++i){
    #pragma unroll
    for (int j = 0; j < NWJ; ++j){
      const int col = nBase + wn*(NWJ*16) + j*16 + cl;
      const float bv = (col < Nb) ? bias[col] : 0.0f;
      #pragma unroll
      for (int r = 0; r < 4; ++r){
        const int row = mBase + wm*64 + i*16 + rqd + r;
        const float v = acc[i][j][r] + bv;
        const size_t o = (size_t)row*N + col;
        if (EPI == 0)      ((uint16_t*)outp)[o] = f2bf(v);
        else if (EPI == 1) ((uint16_t*)outp)[o] = f2bf(gelu_fast(v));
        else               ((float*)outp)[o] = v + res[o];
      }
    }
  }
}

// ---------------- host launcher ----------------
extern "C" void kernel_launch(void* const* d_in, const int* in_sizes, int n_in,
                              void* d_out, int out_size, void* d_ws, size_t ws_size,
                              hipStream_t stream)
{
  const float* x      = (const float*)d_in[0];
  const float* cosb   = (const float*)d_in[1];
  const float* sinb   = (const float*)d_in[2];
  const float* qkv_w  = (const float*)d_in[4];
  const float* qkv_b  = (const float*)d_in[5];
  const float* proj_w = (const float*)d_in[6];
  const float* proj_b = (const float*)d_in[7];
  const float* ln1_w  = (const float*)d_in[8];
  const float* ln1_b  = (const float*)d_in[9];
  const float* ln2_w  = (const float*)d_in[10];
  const float* ln2_b  = (const float*)d_in[11];
  const float* fc1_w  = (const float*)d_in[12];
  const float* fc1_b  = (const float*)d_in[13];
  const float* fc2_w  = (const float*)d_in[14];
  const float* fc2_b  = (const float*)d_in[15];

  char* ws = (char*)d_ws;
  uint16_t* Wqkv  = (uint16_t*)(ws + 0);          // [3456][1152] bf16
  uint16_t* Wproj = (uint16_t*)(ws + 7962624);    // [1152][1152] bf16
  uint16_t* Wfc1  = (uint16_t*)(ws + 10616832);   // [4352][1152] bf16
  uint16_t* Wfc2  = (uint16_t*)(ws + 20643840);   // [1152][4352] bf16
  uint16_t* Hbuf  = (uint16_t*)(ws + 30670848);   // [16384][1152] bf16 (LN out / attn out)
  uint16_t* QKV   = (uint16_t*)(ws + 68419584);   // [16384][3456] bf16
  uint16_t* MB    = QKV;                          // [16384][4352] bf16 overlays QKV
  float* X1 = (float*)d_out;                      // fp32 [16384][1152], residual stream

  // all 4 weight transposes in one dispatch (Bt layout [N][K], zero-padded)
  transpose_cast_all<<<14976, 256, 0, stream>>>(qkv_w, Wqkv, proj_w, Wproj,
                                                fc1_w, Wfc1, fc2_w, Wfc2);

  // LN1 -> Hbuf (bf16)
  ln_kernel<<<4096, 256, 0, stream>>>(x, ln1_w, ln1_b, Hbuf);
  // QKV = Hbuf @ Wqkv^T + b -> bf16 (unrotated; RoPE inside attn). 36x96 n-tiles, 6 exact rounds.
  gemm_bt<0,3><<<36*128, 256, 0, stream>>>(Hbuf, Wqkv, qkv_b, QKVN, nullptr, QKV, QKVN, HID, 36);
  // MFMA windowed attention with fused RoPE -> Hbuf (bf16). 4 blk/CU, 4.0 exact rounds.
  attn_kernel<<<4096, 256, 0, stream>>>(QKV, cosb, sinb, Hbuf);
  // X1 = x + Hbuf @ Wproj^T + b  (fp32, into d_out). 12x96 n-tiles, 2 exact rounds.
  gemm_bt<2,3><<<12*128, 256, 0, stream>>>(Hbuf, Wproj, proj_b, HID, x, X1, HID, HID, 12);
  // LN2 -> Hbuf (bf16)
  ln_kernel<<<4096, 256, 0, stream>>>(X1, ln2_w, ln2_b, Hbuf);
  // MB = gelu(Hbuf @ Wfc1^T + b)  (bf16, padded N=4352: keeps MB K-pad zero for fc2)
  gemm_bt<1,4><<<34*128, 256, 0, stream>>>(Hbuf, Wfc1, fc1_b, INTER, nullptr, MB, INTERP, HID, 34);
  // out = X1 + MB @ Wfc2^T + b   (fp32, in-place on d_out). 12x96 n-tiles, 2 exact rounds.
  gemm_bt<2,3><<<12*128, 256, 0, stream>>>(MB, Wfc2, fc2_b, HID, X1, X1, HID, INTERP, 12);
}

// Round 9
// 1001.585 us; speedup vs baseline: 1.0171x; 1.0171x over previous
//
#include <hip/hip_runtime.h>
#include <stdint.h>

// VisionBlock: LN1 -> QKV GEMM -> [RoPE fused into attn] -> MFMA windowed attn (W=64) -> proj+res -> LN2 -> GELU MLP + res
// bf16 MFMA 16x16x32, fp32 accumulate everywhere.
// GEMM: 128x(32*NWJ) tile, BK=64, global_load_lds w=16, XOR swizzle, XCD-grouped, 3 blk/CU.
// v9: attn staging reverted to v7 exactly (R8 wide-load variant regressed);
//     LN1 merged into the prep mega-dispatch (independent of transposes -> overlap + one less boundary).

#define SEQ   16384
#define HID   1152
#define NH    16
#define HDIM  72
#define INTER 4304
#define INTERP 4352
#define QKVN  3456

using bf16x8 = __attribute__((ext_vector_type(8))) __bf16;
using f32x4  = __attribute__((ext_vector_type(4))) float;

__device__ __forceinline__ float bf2f(uint16_t u){ return __uint_as_float(((uint32_t)u)<<16); }
__device__ __forceinline__ uint16_t f2bf(float f){
  uint32_t u = __float_as_uint(f);
  u += 0x7fffu + ((u>>16)&1u);
  return (uint16_t)(u>>16);
}
__device__ __forceinline__ uint32_t pk2(uint16_t a, uint16_t b){ return (uint32_t)a | ((uint32_t)b<<16); }
// 0.5x(1+tanh(0.79788456(x+0.044715x^3))) == x*sigmoid(1.59576912(x+0.044715x^3))
__device__ __forceinline__ float gelu_fast(float x){
  const float z = 2.3022085f * x * (1.0f + 0.044715f*x*x);
  return x / (1.0f + exp2f(-z));
}
__device__ __forceinline__ void async_load16(const void* g, void* l){
  __builtin_amdgcn_global_load_lds((__attribute__((address_space(1))) void*)(void*)g,
                                   (__attribute__((address_space(3))) void*)l, 16, 0, 0);
}

__device__ __forceinline__ void ln_row_body(const float* __restrict__ x, const float* __restrict__ w,
                                            const float* __restrict__ b, uint16_t* __restrict__ out,
                                            int row, int lane)
{
  const float2* xr = (const float2*)(x + (size_t)row*HID);
  float2 v[9];
  float s = 0.f;
  #pragma unroll
  for (int t = 0; t < 9; ++t){ v[t] = xr[lane + t*64]; s += v[t].x + v[t].y; }
  #pragma unroll
  for (int m = 32; m; m >>= 1) s += __shfl_xor(s, m, 64);
  const float mean = s * (1.0f/HID);
  float q = 0.f;
  #pragma unroll
  for (int t = 0; t < 9; ++t){
    float dx = v[t].x-mean, dy = v[t].y-mean;
    q += dx*dx + dy*dy;
  }
  #pragma unroll
  for (int m = 32; m; m >>= 1) q += __shfl_xor(q, m, 64);
  const float rstd = rsqrtf(q*(1.0f/HID) + 1e-6f);
  const float2* w2 = (const float2*)w;
  const float2* b2 = (const float2*)b;
  uint32_t* orow = (uint32_t*)(out + (size_t)row*HID);
  #pragma unroll
  for (int t = 0; t < 9; ++t){
    const int j = lane + t*64;
    const float2 wv = w2[j], bv = b2[j];
    const float o0 = (v[t].x-mean)*rstd*wv.x + bv.x;
    const float o1 = (v[t].y-mean)*rstd*wv.y + bv.y;
    orow[j] = (uint32_t)f2bf(o0) | ((uint32_t)f2bf(o1)<<16);
  }
}

// ---------------- prep mega-dispatch: LN1 (job L) + 4 weight transposes (jobs 0..3) ----------------
// blocks 0..4095           : LN1 rows (4 rows/block, one wave each)  [independent of transposes]
// blocks 4096..7983        : qkv  transpose, grid 108x36
// blocks 7984..9279        : proj transpose, grid  36x36
// blocks 9280..14175       : fc1  transpose, grid 136x36
// blocks 14176..19071      : fc2  transpose, grid  36x136
__global__ void prep_kernel(const float* __restrict__ x,  const float* __restrict__ ln1w,
                            const float* __restrict__ ln1b, uint16_t* __restrict__ hout,
                            const float* __restrict__ s0, uint16_t* __restrict__ d0,
                            const float* __restrict__ s1, uint16_t* __restrict__ d1,
                            const float* __restrict__ s2, uint16_t* __restrict__ d2,
                            const float* __restrict__ s3, uint16_t* __restrict__ d3)
{
  __shared__ float tile[32][33];
  int b = blockIdx.x;
  if (b < 4096){
    const int wid = threadIdx.x >> 6, lane = threadIdx.x & 63;
    ln_row_body(x, ln1w, ln1b, hout, b*4 + wid, lane);
    return;
  }
  b -= 4096;
  const float* src; uint16_t* dst; int R, C, Rp, bx, by;
  if (b < 3888){        src = s0; dst = d0; R = 1152; C = 3456; Rp = 1152; bx = b % 108; by = b / 108; }
  else if (b < 5184){   b -= 3888; src = s1; dst = d1; R = 1152; C = 1152; Rp = 1152; bx = b % 36; by = b / 36; }
  else if (b < 10080){  b -= 5184; src = s2; dst = d2; R = 1152; C = 4304; Rp = 1152; bx = b % 136; by = b / 136; }
  else {                b -= 10080; src = s3; dst = d3; R = 4304; C = 1152; Rp = 4352; bx = b % 36; by = b / 36; }
  const int tx = threadIdx.x & 31, ty = threadIdx.x >> 5;
  const int c = bx*32 + tx;
  #pragma unroll
  for (int s = 0; s < 4; ++s){
    const int r = by*32 + ty + s*8;
    tile[ty + s*8][tx] = (r < R && c < C) ? src[(size_t)r*C + c] : 0.0f;
  }
  __syncthreads();
  #pragma unroll
  for (int s = 0; s < 4; ++s){
    const int oc = bx*32 + ty + s*8;     // output row  (N dim)
    const int orr = by*32 + tx;          // output col  (K dim)
    dst[(size_t)oc*Rp + orr] = f2bf(tile[tx][ty + s*8]);
  }
}

// ---------------- LayerNorm standalone (used for LN2) ----------------
__global__ void ln_kernel(const float* __restrict__ x, const float* __restrict__ w,
                          const float* __restrict__ b, uint16_t* __restrict__ out)
{
  const int wid = threadIdx.x >> 6, lane = threadIdx.x & 63;
  ln_row_body(x, w, b, out, blockIdx.x*4 + wid, lane);
}

// ---------------- MFMA windowed attention with fused RoPE: one block per (window, head) ----------------
// Layouts (bf16 LDS):
//   Qb[64][104]: rows = tokens, cols = dims, dims 72..95 zeroed (K-pad), stride 104.
//     After QK^T, cols 0..63 of each row are REUSED as P (probs row-major, stride 104):
//     wave wv reads/writes only rows wv*16..+15 of Q and P -> wave-private, no barrier needed.
//   Kb[64][104]: same layout as Qb (all rows read by all waves).
//   Vt[80][72-stride]: rows = dims (72 real + 8 zero pad), cols = tokens.
// Per wave (4 waves): 16-row strip. QK^T: 3 k-steps x 4 n-tiles = 12 MFMA. Softmax on C/D
// layout (col=lane&15, row=(lane>>4)*4+reg), shfl_xor width-16 -> P bf16. PV: 2 k-steps x
// 5 n-tiles = 10 MFMA. setprio(1) around MFMA clusters (waves independent post-staging).
__global__ __launch_bounds__(256,4) void attn_kernel(const uint16_t* __restrict__ qkv,
                                                     const float* __restrict__ cosb,
                                                     const float* __restrict__ sinb,
                                                     uint16_t* __restrict__ outb)
{
  __shared__ uint16_t Qb[64*104];   // Q, then P overlays cols 0..63
  __shared__ uint16_t Kb[64*104];
  __shared__ uint16_t Vt[80*72];
  const int tid = threadIdx.x;
  const int win = blockIdx.x >> 4, h = blockIdx.x & 15;
  const size_t base = (size_t)win*64*QKVN + h*HDIM;
  // ---- staging: RoPE(Q,K) -> bf16, V transposed ----
  {
    const int r = tid >> 2, q4 = tid & 3;
    const size_t rb = base + (size_t)r*QKVN;
    const float* crow = cosb + (size_t)(win*64 + r)*HDIM;
    const float* srow = sinb + (size_t)(win*64 + r)*HDIM;
    const int isK = q4 >> 1;
    const size_t mb = rb + (size_t)(isK ? HID : 0);
    uint16_t* dst = isK ? &Kb[r*104] : &Qb[r*104];
    const int pb = (q4 & 1)*9;
    #pragma unroll
    for (int p0 = 0; p0 < 9; ++p0){
      const int d0 = (pb + p0)*2;
      const uint32_t ulo = *(const uint32_t*)(qkv + mb + d0);
      const uint32_t uhi = *(const uint32_t*)(qkv + mb + d0 + 36);
      const float2 c2 = *(const float2*)(crow + d0);
      const float2 s2 = *(const float2*)(srow + d0);
      const float l0 = bf2f((uint16_t)ulo), l1 = bf2f((uint16_t)(ulo>>16));
      const float h0 = bf2f((uint16_t)uhi), h1 = bf2f((uint16_t)(uhi>>16));
      *(uint32_t*)&dst[d0]    = pk2(f2bf(l0*c2.x - h0*s2.x), f2bf(l1*c2.y - h1*s2.y));
      *(uint32_t*)&dst[d0+36] = pk2(f2bf(h0*c2.x + l0*s2.x), f2bf(h1*c2.y + l1*s2.y));
    }
    // zero dims 72..95 of this row (12 uint32 split between the 2 threads per matrix)
    const int zb = (q4 & 1)*6;
    #pragma unroll
    for (int z = 0; z < 6; ++z) *(uint32_t*)&dst[72 + (zb + z)*2] = 0;
    // V transposed: dims 2p,2p+1 of token r
    #pragma unroll
    for (int p0 = 0; p0 < 9; ++p0){
      const int p = q4*9 + p0;
      const uint32_t uv = *(const uint32_t*)(qkv + rb + 2*HID + 2*p);
      Vt[(2*p+0)*72 + r] = (uint16_t)uv;
      Vt[(2*p+1)*72 + r] = (uint16_t)(uv>>16);
    }
  }
  // zero Vt pad rows 72..79 (8 dims x 64 tokens = 256 uint32, one per thread)
  {
    const int d = 72 + (tid >> 5), t = (tid & 31)*2;
    *(uint32_t*)&Vt[d*72 + t] = 0;
  }
  __syncthreads();

  const int wv = tid >> 6, lane = tid & 63;
  const int fr = lane & 15, fq = lane >> 4;
  // ---- QK^T: scores strip rows wv*16..+15, cols 0..63 ----
  f32x4 sacc[4] = {};
  __builtin_amdgcn_s_setprio(1);
  #pragma unroll
  for (int ks = 0; ks < 3; ++ks){
    const bf16x8 aq = *(const bf16x8*)&Qb[(wv*16 + fr)*104 + ks*32 + fq*8];
    #pragma unroll
    for (int j = 0; j < 4; ++j){
      const bf16x8 bk = *(const bf16x8*)&Kb[(j*16 + fr)*104 + ks*32 + fq*8];
      sacc[j] = __builtin_amdgcn_mfma_f32_16x16x32_bf16(aq, bk, sacc[j], 0, 0, 0);
    }
  }
  __builtin_amdgcn_s_setprio(0);
  // ---- softmax on C/D layout; write P (bf16) into Qb cols 0..63 (own strip only) ----
  const float scale = 0.11785113019775793f;   // 72^-0.5
  #pragma unroll
  for (int r = 0; r < 4; ++r){
    float a0 = sacc[0][r]*scale, a1 = sacc[1][r]*scale, a2 = sacc[2][r]*scale, a3 = sacc[3][r]*scale;
    float m = fmaxf(fmaxf(a0,a1), fmaxf(a2,a3));
    m = fmaxf(m, __shfl_xor(m, 1, 16));
    m = fmaxf(m, __shfl_xor(m, 2, 16));
    m = fmaxf(m, __shfl_xor(m, 4, 16));
    m = fmaxf(m, __shfl_xor(m, 8, 16));
    float e0 = __expf(a0-m), e1 = __expf(a1-m), e2 = __expf(a2-m), e3 = __expf(a3-m);
    float sm = e0+e1+e2+e3;
    sm += __shfl_xor(sm, 1, 16);
    sm += __shfl_xor(sm, 2, 16);
    sm += __shfl_xor(sm, 4, 16);
    sm += __shfl_xor(sm, 8, 16);
    const float inv = 1.0f/sm;
    const int prow = wv*16 + fq*4 + r;
    Qb[prow*104 +  0 + fr] = f2bf(e0*inv);
    Qb[prow*104 + 16 + fr] = f2bf(e1*inv);
    Qb[prow*104 + 32 + fr] = f2bf(e2*inv);
    Qb[prow*104 + 48 + fr] = f2bf(e3*inv);
  }
  // P rows wv*16..+15 are written and read by wave wv only -> no barrier needed.
  // ---- PV: out strip rows wv*16..+15, dims 0..71 (5 n-tiles, last half-padded) ----
  f32x4 oacc[5] = {};
  __builtin_amdgcn_s_setprio(1);
  #pragma unroll
  for (int k2 = 0; k2 < 2; ++k2){
    const bf16x8 ap = *(const bf16x8*)&Qb[(wv*16 + fr)*104 + k2*32 + fq*8];
    #pragma unroll
    for (int j = 0; j < 5; ++j){
      const bf16x8 bv = *(const bf16x8*)&Vt[(j*16 + fr)*72 + k2*32 + fq*8];
      oacc[j] = __builtin_amdgcn_mfma_f32_16x16x32_bf16(ap, bv, oacc[j], 0, 0, 0);
    }
  }
  __builtin_amdgcn_s_setprio(0);
  // ---- store: C/D layout col=dim, row=token ----
  #pragma unroll
  for (int j = 0; j < 5; ++j){
    const int d = j*16 + fr;
    if (d < HDIM){
      #pragma unroll
      for (int r = 0; r < 4; ++r){
        const int token = win*64 + wv*16 + fq*4 + r;
        outb[(size_t)token*HID + h*HDIM + d] = f2bf(oacc[j][r]);
      }
    }
  }
}

// ---------------- bf16 GEMM: C[M][N] = A[M][K] @ Bt[N][K]^T ----------------
// 128 x (32*NWJ) tile, BK=64, 1D grid (NB*MB, multiple of 8), XCD-grouped tiles.
// XOR swizzle: physical 8-elem slot k holds logical chunk k ^ ((row>>1)&3) (0 conflicts measured).
// NWJ=4: 128-wide n-tile; NWJ=3: 96-wide (integral rounds at 3 blk/CU for qkv/proj/fc2).
// EPI: 0 = bf16(bias), 1 = bf16(gelu(bias)), 2 = f32(bias + residual)
template<int EPI, int NWJ>
__global__ __launch_bounds__(256,3) void gemm_bt(
    const uint16_t* __restrict__ A, const uint16_t* __restrict__ Bt,
    const float* __restrict__ bias, int Nb,
    const float* res, void* outp, int N, int K, int NB)
{
  __shared__ uint16_t sA[128*64];
  __shared__ uint16_t sB[32*NWJ*64];
  const int tid = threadIdx.x, wid = tid >> 6, lane = tid & 63;
  const int per  = gridDim.x >> 3;
  const int tile = (blockIdx.x & 7)*per + (blockIdx.x >> 3);
  const int mb   = tile / NB;
  const int mBase = mb*128, nBase = (tile - mb*NB)*(32*NWJ);
  const int wm = wid >> 1, wn = wid & 1;
  const int sr = lane >> 2;
  const int sk = lane & 3;
  const int gk = sk ^ ((sr >> 1) & 3);
  const int rr = lane & 15;
  const int rq = lane >> 4;
  const int rp = rq ^ ((rr >> 1) & 3);
  f32x4 acc[4][NWJ] = {};

  for (int k0 = 0; k0 < K; k0 += 64){
    __syncthreads();
    #pragma unroll
    for (int j = 0; j < 4; ++j){
      const int c  = wid*4 + j;
      const int rc = c >> 1, h = c & 1;
      const size_t gcol = (size_t)(k0 + h*32 + gk*8);
      async_load16(A + (size_t)(mBase + rc*16 + sr)*K + gcol, &sA[c*512]);
    }
    #pragma unroll
    for (int j = 0; j < NWJ; ++j){
      const int c  = wid*NWJ + j;
      const int rc = c >> 1, h = c & 1;
      const size_t gcol = (size_t)(k0 + h*32 + gk*8);
      async_load16(Bt + (size_t)(nBase + rc*16 + sr)*K + gcol, &sB[c*512]);
    }
    __syncthreads();
    #pragma unroll
    for (int h = 0; h < 2; ++h){
      bf16x8 af[4], bfr[NWJ];
      #pragma unroll
      for (int i = 0; i < 4; ++i)
        af[i] = *(const bf16x8*)&sA[((wm*4 + i)*2 + h)*512 + rr*32 + rp*8];
      #pragma unroll
      for (int j = 0; j < NWJ; ++j)
        bfr[j] = *(const bf16x8*)&sB[((wn*NWJ + j)*2 + h)*512 + rr*32 + rp*8];
      #pragma unroll
      for (int i = 0; i < 4; ++i)
        #pragma unroll
        for (int j = 0; j < NWJ; ++j)
          acc[i][j] = __builtin_amdgcn_mfma_f32_16x16x32_bf16(af[i], bfr[j], acc[i][j], 0, 0, 0);
    }
  }

  const int rqd = (lane>>4)*4, cl = lane & 15;
  #pragma unroll
  for (int i = 0; i < 4; ++i){
    #pragma unroll
    for (int j = 0; j < NWJ; ++j){
      const int col = nBase + wn*(NWJ*16) + j*16 + cl;
      const float bv = (col < Nb) ? bias[col] : 0.0f;
      #pragma unroll
      for (int r = 0; r < 4; ++r){
        const int row = mBase + wm*64 + i*16 + rqd + r;
        const float v = acc[i][j][r] + bv;
        const size_t o = (size_t)row*N + col;
        if (EPI == 0)      ((uint16_t*)outp)[o] = f2bf(v);
        else if (EPI == 1) ((uint16_t*)outp)[o] = f2bf(gelu_fast(v));
        else               ((float*)outp)[o] = v + res[o];
      }
    }
  }
}

// ---------------- host launcher ----------------
extern "C" void kernel_launch(void* const* d_in, const int* in_sizes, int n_in,
                              void* d_out, int out_size, void* d_ws, size_t ws_size,
                              hipStream_t stream)
{
  const float* x      = (const float*)d_in[0];
  const float* cosb   = (const float*)d_in[1];
  const float* sinb   = (const float*)d_in[2];
  const float* qkv_w  = (const float*)d_in[4];
  const float* qkv_b  = (const float*)d_in[5];
  const float* proj_w = (const float*)d_in[6];
  const float* proj_b = (const float*)d_in[7];
  const float* ln1_w  = (const float*)d_in[8];
  const float* ln1_b  = (const float*)d_in[9];
  const float* ln2_w  = (const float*)d_in[10];
  const float* ln2_b  = (const float*)d_in[11];
  const float* fc1_w  = (const float*)d_in[12];
  const float* fc1_b  = (const float*)d_in[13];
  const float* fc2_w  = (const float*)d_in[14];
  const float* fc2_b  = (const float*)d_in[15];

  char* ws = (char*)d_ws;
  uint16_t* Wqkv  = (uint16_t*)(ws + 0);          // [3456][1152] bf16
  uint16_t* Wproj = (uint16_t*)(ws + 7962624);    // [1152][1152] bf16
  uint16_t* Wfc1  = (uint16_t*)(ws + 10616832);   // [4352][1152] bf16
  uint16_t* Wfc2  = (uint16_t*)(ws + 20643840);   // [1152][4352] bf16
  uint16_t* Hbuf  = (uint16_t*)(ws + 30670848);   // [16384][1152] bf16 (LN out / attn out)
  uint16_t* QKV   = (uint16_t*)(ws + 68419584);   // [16384][3456] bf16
  uint16_t* MB    = QKV;                          // [16384][4352] bf16 overlays QKV
  float* X1 = (float*)d_out;                      // fp32 [16384][1152], residual stream

  // prep: LN1 (blocks 0..4095) + all 4 weight transposes, one dispatch
  prep_kernel<<<19072, 256, 0, stream>>>(x, ln1_w, ln1_b, Hbuf,
                                         qkv_w, Wqkv, proj_w, Wproj,
                                         fc1_w, Wfc1, fc2_w, Wfc2);

  // QKV = Hbuf @ Wqkv^T + b -> bf16 (unrotated; RoPE inside attn). 36x96 n-tiles, 6 exact rounds.
  gemm_bt<0,3><<<36*128, 256, 0, stream>>>(Hbuf, Wqkv, qkv_b, QKVN, nullptr, QKV, QKVN, HID, 36);
  // MFMA windowed attention with fused RoPE -> Hbuf (bf16). 4 blk/CU, 4.0 exact rounds.
  attn_kernel<<<4096, 256, 0, stream>>>(QKV, cosb, sinb, Hbuf);
  // X1 = x + Hbuf @ Wproj^T + b  (fp32, into d_out). 12x96 n-tiles, 2 exact rounds.
  gemm_bt<2,3><<<12*128, 256, 0, stream>>>(Hbuf, Wproj, proj_b, HID, x, X1, HID, HID, 12);
  // LN2 -> Hbuf (bf16)
  ln_kernel<<<4096, 256, 0, stream>>>(X1, ln2_w, ln2_b, Hbuf);
  // MB = gelu(Hbuf @ Wfc1^T + b)  (bf16, padded N=4352: keeps MB K-pad zero for fc2)
  gemm_bt<1,4><<<34*128, 256, 0, stream>>>(Hbuf, Wfc1, fc1_b, INTER, nullptr, MB, INTERP, HID, 34);
  // out = X1 + MB @ Wfc2^T + b   (fp32, in-place on d_out). 12x96 n-tiles, 2 exact rounds.
  gemm_bt<2,3><<<12*128, 256, 0, stream>>>(MB, Wfc2, fc2_b, HID, X1, X1, HID, INTERP, 12);
}

// Round 10
// 997.520 us; speedup vs baseline: 1.0213x; 1.0041x over previous
//
#include <hip/hip_runtime.h>
#include <stdint.h>

// VisionBlock: LN1 -> QKV GEMM -> [RoPE fused into attn] -> MFMA windowed attn (W=64) -> proj+res -> LN2 -> GELU MLP + res
// bf16 MFMA 16x16x32, fp32 accumulate everywhere.
// GEMM: 128x(32*NWJ) tile, BK=64, global_load_lds w=16, XOR swizzle, XCD-grouped, 3 blk/CU.
// v10: per-block start-skew (s_sleep 0/256/512 cyc by (blockIdx>>3)%3) to break the
//      3-co-resident-block phase lock on the per-K-tile vmcnt drain (MfmaUtil 29% ~= single
//      block's share; staggered phases should overlap drain with other blocks' MFMA).
//      Everything else identical to v9.

#define SEQ   16384
#define HID   1152
#define NH    16
#define HDIM  72
#define INTER 4304
#define INTERP 4352
#define QKVN  3456

using bf16x8 = __attribute__((ext_vector_type(8))) __bf16;
using f32x4  = __attribute__((ext_vector_type(4))) float;

__device__ __forceinline__ float bf2f(uint16_t u){ return __uint_as_float(((uint32_t)u)<<16); }
__device__ __forceinline__ uint16_t f2bf(float f){
  uint32_t u = __float_as_uint(f);
  u += 0x7fffu + ((u>>16)&1u);
  return (uint16_t)(u>>16);
}
__device__ __forceinline__ uint32_t pk2(uint16_t a, uint16_t b){ return (uint32_t)a | ((uint32_t)b<<16); }
// 0.5x(1+tanh(0.79788456(x+0.044715x^3))) == x*sigmoid(1.59576912(x+0.044715x^3))
__device__ __forceinline__ float gelu_fast(float x){
  const float z = 2.3022085f * x * (1.0f + 0.044715f*x*x);
  return x / (1.0f + exp2f(-z));
}
__device__ __forceinline__ void async_load16(const void* g, void* l){
  __builtin_amdgcn_global_load_lds((__attribute__((address_space(1))) void*)(void*)g,
                                   (__attribute__((address_space(3))) void*)l, 16, 0, 0);
}

__device__ __forceinline__ void ln_row_body(const float* __restrict__ x, const float* __restrict__ w,
                                            const float* __restrict__ b, uint16_t* __restrict__ out,
                                            int row, int lane)
{
  const float2* xr = (const float2*)(x + (size_t)row*HID);
  float2 v[9];
  float s = 0.f;
  #pragma unroll
  for (int t = 0; t < 9; ++t){ v[t] = xr[lane + t*64]; s += v[t].x + v[t].y; }
  #pragma unroll
  for (int m = 32; m; m >>= 1) s += __shfl_xor(s, m, 64);
  const float mean = s * (1.0f/HID);
  float q = 0.f;
  #pragma unroll
  for (int t = 0; t < 9; ++t){
    float dx = v[t].x-mean, dy = v[t].y-mean;
    q += dx*dx + dy*dy;
  }
  #pragma unroll
  for (int m = 32; m; m >>= 1) q += __shfl_xor(q, m, 64);
  const float rstd = rsqrtf(q*(1.0f/HID) + 1e-6f);
  const float2* w2 = (const float2*)w;
  const float2* b2 = (const float2*)b;
  uint32_t* orow = (uint32_t*)(out + (size_t)row*HID);
  #pragma unroll
  for (int t = 0; t < 9; ++t){
    const int j = lane + t*64;
    const float2 wv = w2[j], bv = b2[j];
    const float o0 = (v[t].x-mean)*rstd*wv.x + bv.x;
    const float o1 = (v[t].y-mean)*rstd*wv.y + bv.y;
    orow[j] = (uint32_t)f2bf(o0) | ((uint32_t)f2bf(o1)<<16);
  }
}

// ---------------- prep mega-dispatch: LN1 (job L) + 4 weight transposes (jobs 0..3) ----------------
// blocks 0..4095           : LN1 rows (4 rows/block, one wave each)  [independent of transposes]
// blocks 4096..7983        : qkv  transpose, grid 108x36
// blocks 7984..9279        : proj transpose, grid  36x36
// blocks 9280..14175       : fc1  transpose, grid 136x36
// blocks 14176..19071      : fc2  transpose, grid  36x136
__global__ void prep_kernel(const float* __restrict__ x,  const float* __restrict__ ln1w,
                            const float* __restrict__ ln1b, uint16_t* __restrict__ hout,
                            const float* __restrict__ s0, uint16_t* __restrict__ d0,
                            const float* __restrict__ s1, uint16_t* __restrict__ d1,
                            const float* __restrict__ s2, uint16_t* __restrict__ d2,
                            const float* __restrict__ s3, uint16_t* __restrict__ d3)
{
  __shared__ float tile[32][33];
  int b = blockIdx.x;
  if (b < 4096){
    const int wid = threadIdx.x >> 6, lane = threadIdx.x & 63;
    ln_row_body(x, ln1w, ln1b, hout, b*4 + wid, lane);
    return;
  }
  b -= 4096;
  const float* src; uint16_t* dst; int R, C, Rp, bx, by;
  if (b < 3888){        src = s0; dst = d0; R = 1152; C = 3456; Rp = 1152; bx = b % 108; by = b / 108; }
  else if (b < 5184){   b -= 3888; src = s1; dst = d1; R = 1152; C = 1152; Rp = 1152; bx = b % 36; by = b / 36; }
  else if (b < 10080){  b -= 5184; src = s2; dst = d2; R = 1152; C = 4304; Rp = 1152; bx = b % 136; by = b / 136; }
  else {                b -= 10080; src = s3; dst = d3; R = 4304; C = 1152; Rp = 4352; bx = b % 36; by = b / 36; }
  const int tx = threadIdx.x & 31, ty = threadIdx.x >> 5;
  const int c = bx*32 + tx;
  #pragma unroll
  for (int s = 0; s < 4; ++s){
    const int r = by*32 + ty + s*8;
    tile[ty + s*8][tx] = (r < R && c < C) ? src[(size_t)r*C + c] : 0.0f;
  }
  __syncthreads();
  #pragma unroll
  for (int s = 0; s < 4; ++s){
    const int oc = bx*32 + ty + s*8;     // output row  (N dim)
    const int orr = by*32 + tx;          // output col  (K dim)
    dst[(size_t)oc*Rp + orr] = f2bf(tile[tx][ty + s*8]);
  }
}

// ---------------- LayerNorm standalone (used for LN2) ----------------
__global__ void ln_kernel(const float* __restrict__ x, const float* __restrict__ w,
                          const float* __restrict__ b, uint16_t* __restrict__ out)
{
  const int wid = threadIdx.x >> 6, lane = threadIdx.x & 63;
  ln_row_body(x, w, b, out, blockIdx.x*4 + wid, lane);
}

// ---------------- MFMA windowed attention with fused RoPE: one block per (window, head) ----------------
// Layouts (bf16 LDS):
//   Qb[64][104]: rows = tokens, cols = dims, dims 72..95 zeroed (K-pad), stride 104.
//     After QK^T, cols 0..63 of each row are REUSED as P (probs row-major, stride 104):
//     wave wv reads/writes only rows wv*16..+15 of Q and P -> wave-private, no barrier needed.
//   Kb[64][104]: same layout as Qb (all rows read by all waves).
//   Vt[80][72-stride]: rows = dims (72 real + 8 zero pad), cols = tokens.
// Per wave (4 waves): 16-row strip. QK^T: 3 k-steps x 4 n-tiles = 12 MFMA. Softmax on C/D
// layout (col=lane&15, row=(lane>>4)*4+reg), shfl_xor width-16 -> P bf16. PV: 2 k-steps x
// 5 n-tiles = 10 MFMA. setprio(1) around MFMA clusters (waves independent post-staging).
__global__ __launch_bounds__(256,4) void attn_kernel(const uint16_t* __restrict__ qkv,
                                                     const float* __restrict__ cosb,
                                                     const float* __restrict__ sinb,
                                                     uint16_t* __restrict__ outb)
{
  __shared__ uint16_t Qb[64*104];   // Q, then P overlays cols 0..63
  __shared__ uint16_t Kb[64*104];
  __shared__ uint16_t Vt[80*72];
  const int tid = threadIdx.x;
  const int win = blockIdx.x >> 4, h = blockIdx.x & 15;
  const size_t base = (size_t)win*64*QKVN + h*HDIM;
  // ---- staging: RoPE(Q,K) -> bf16, V transposed ----
  {
    const int r = tid >> 2, q4 = tid & 3;
    const size_t rb = base + (size_t)r*QKVN;
    const float* crow = cosb + (size_t)(win*64 + r)*HDIM;
    const float* srow = sinb + (size_t)(win*64 + r)*HDIM;
    const int isK = q4 >> 1;
    const size_t mb = rb + (size_t)(isK ? HID : 0);
    uint16_t* dst = isK ? &Kb[r*104] : &Qb[r*104];
    const int pb = (q4 & 1)*9;
    #pragma unroll
    for (int p0 = 0; p0 < 9; ++p0){
      const int d0 = (pb + p0)*2;
      const uint32_t ulo = *(const uint32_t*)(qkv + mb + d0);
      const uint32_t uhi = *(const uint32_t*)(qkv + mb + d0 + 36);
      const float2 c2 = *(const float2*)(crow + d0);
      const float2 s2 = *(const float2*)(srow + d0);
      const float l0 = bf2f((uint16_t)ulo), l1 = bf2f((uint16_t)(ulo>>16));
      const float h0 = bf2f((uint16_t)uhi), h1 = bf2f((uint16_t)(uhi>>16));
      *(uint32_t*)&dst[d0]    = pk2(f2bf(l0*c2.x - h0*s2.x), f2bf(l1*c2.y - h1*s2.y));
      *(uint32_t*)&dst[d0+36] = pk2(f2bf(h0*c2.x + l0*s2.x), f2bf(h1*c2.y + l1*s2.y));
    }
    // zero dims 72..95 of this row (12 uint32 split between the 2 threads per matrix)
    const int zb = (q4 & 1)*6;
    #pragma unroll
    for (int z = 0; z < 6; ++z) *(uint32_t*)&dst[72 + (zb + z)*2] = 0;
    // V transposed: dims 2p,2p+1 of token r
    #pragma unroll
    for (int p0 = 0; p0 < 9; ++p0){
      const int p = q4*9 + p0;
      const uint32_t uv = *(const uint32_t*)(qkv + rb + 2*HID + 2*p);
      Vt[(2*p+0)*72 + r] = (uint16_t)uv;
      Vt[(2*p+1)*72 + r] = (uint16_t)(uv>>16);
    }
  }
  // zero Vt pad rows 72..79 (8 dims x 64 tokens = 256 uint32, one per thread)
  {
    const int d = 72 + (tid >> 5), t = (tid & 31)*2;
    *(uint32_t*)&Vt[d*72 + t] = 0;
  }
  __syncthreads();

  const int wv = tid >> 6, lane = tid & 63;
  const int fr = lane & 15, fq = lane >> 4;
  // ---- QK^T: scores strip rows wv*16..+15, cols 0..63 ----
  f32x4 sacc[4] = {};
  __builtin_amdgcn_s_setprio(1);
  #pragma unroll
  for (int ks = 0; ks < 3; ++ks){
    const bf16x8 aq = *(const bf16x8*)&Qb[(wv*16 + fr)*104 + ks*32 + fq*8];
    #pragma unroll
    for (int j = 0; j < 4; ++j){
      const bf16x8 bk = *(const bf16x8*)&Kb[(j*16 + fr)*104 + ks*32 + fq*8];
      sacc[j] = __builtin_amdgcn_mfma_f32_16x16x32_bf16(aq, bk, sacc[j], 0, 0, 0);
    }
  }
  __builtin_amdgcn_s_setprio(0);
  // ---- softmax on C/D layout; write P (bf16) into Qb cols 0..63 (own strip only) ----
  const float scale = 0.11785113019775793f;   // 72^-0.5
  #pragma unroll
  for (int r = 0; r < 4; ++r){
    float a0 = sacc[0][r]*scale, a1 = sacc[1][r]*scale, a2 = sacc[2][r]*scale, a3 = sacc[3][r]*scale;
    float m = fmaxf(fmaxf(a0,a1), fmaxf(a2,a3));
    m = fmaxf(m, __shfl_xor(m, 1, 16));
    m = fmaxf(m, __shfl_xor(m, 2, 16));
    m = fmaxf(m, __shfl_xor(m, 4, 16));
    m = fmaxf(m, __shfl_xor(m, 8, 16));
    float e0 = __expf(a0-m), e1 = __expf(a1-m), e2 = __expf(a2-m), e3 = __expf(a3-m);
    float sm = e0+e1+e2+e3;
    sm += __shfl_xor(sm, 1, 16);
    sm += __shfl_xor(sm, 2, 16);
    sm += __shfl_xor(sm, 4, 16);
    sm += __shfl_xor(sm, 8, 16);
    const float inv = 1.0f/sm;
    const int prow = wv*16 + fq*4 + r;
    Qb[prow*104 +  0 + fr] = f2bf(e0*inv);
    Qb[prow*104 + 16 + fr] = f2bf(e1*inv);
    Qb[prow*104 + 32 + fr] = f2bf(e2*inv);
    Qb[prow*104 + 48 + fr] = f2bf(e3*inv);
  }
  // P rows wv*16..+15 are written and read by wave wv only -> no barrier needed.
  // ---- PV: out strip rows wv*16..+15, dims 0..71 (5 n-tiles, last half-padded) ----
  f32x4 oacc[5] = {};
  __builtin_amdgcn_s_setprio(1);
  #pragma unroll
  for (int k2 = 0; k2 < 2; ++k2){
    const bf16x8 ap = *(const bf16x8*)&Qb[(wv*16 + fr)*104 + k2*32 + fq*8];
    #pragma unroll
    for (int j = 0; j < 5; ++j){
      const bf16x8 bv = *(const bf16x8*)&Vt[(j*16 + fr)*72 + k2*32 + fq*8];
      oacc[j] = __builtin_amdgcn_mfma_f32_16x16x32_bf16(ap, bv, oacc[j], 0, 0, 0);
    }
  }
  __builtin_amdgcn_s_setprio(0);
  // ---- store: C/D layout col=dim, row=token ----
  #pragma unroll
  for (int j = 0; j < 5; ++j){
    const int d = j*16 + fr;
    if (d < HDIM){
      #pragma unroll
      for (int r = 0; r < 4; ++r){
        const int token = win*64 + wv*16 + fq*4 + r;
        outb[(size_t)token*HID + h*HDIM + d] = f2bf(oacc[j][r]);
      }
    }
  }
}

// ---------------- bf16 GEMM: C[M][N] = A[M][K] @ Bt[N][K]^T ----------------
// 128 x (32*NWJ) tile, BK=64, 1D grid (NB*MB, multiple of 8), XCD-grouped tiles.
// XOR swizzle: physical 8-elem slot k holds logical chunk k ^ ((row>>1)&3) (0 conflicts measured).
// NWJ=4: 128-wide n-tile; NWJ=3: 96-wide (integral rounds at 3 blk/CU for qkv/proj/fc2).
// v10: one-time start-skew of ~0/256/512 cyc by (blockIdx>>3)%3 so the 3 co-resident blocks
// on a CU run phase-shifted K-tile loops (drain of one overlaps MFMA of the others).
// EPI: 0 = bf16(bias), 1 = bf16(gelu(bias)), 2 = f32(bias + residual)
template<int EPI, int NWJ>
__global__ __launch_bounds__(256,3) void gemm_bt(
    const uint16_t* __restrict__ A, const uint16_t* __restrict__ Bt,
    const float* __restrict__ bias, int Nb,
    const float* res, void* outp, int N, int K, int NB)
{
  __shared__ uint16_t sA[128*64];
  __shared__ uint16_t sB[32*NWJ*64];
  // start-skew: distinct phases for co-resident blocks under either consecutive or
  // stride-32 CU fill order ({c,c+1,c+2} and {c,c+32,c+64} both hit all 3 residues mod 3).
  {
    const int ph = (blockIdx.x >> 3) % 3;
    if (ph == 1)      __builtin_amdgcn_s_sleep(4);   // ~256 cyc
    else if (ph == 2) __builtin_amdgcn_s_sleep(8);   // ~512 cyc
  }
  const int tid = threadIdx.x, wid = tid >> 6, lane = tid & 63;
  const int per  = gridDim.x >> 3;
  const int tile = (blockIdx.x & 7)*per + (blockIdx.x >> 3);
  const int mb   = tile / NB;
  const int mBase = mb*128, nBase = (tile - mb*NB)*(32*NWJ);
  const int wm = wid >> 1, wn = wid & 1;
  const int sr = lane >> 2;
  const int sk = lane & 3;
  const int gk = sk ^ ((sr >> 1) & 3);
  const int rr = lane & 15;
  const int rq = lane >> 4;
  const int rp = rq ^ ((rr >> 1) & 3);
  f32x4 acc[4][NWJ] = {};

  for (int k0 = 0; k0 < K; k0 += 64){
    __syncthreads();
    #pragma unroll
    for (int j = 0; j < 4; ++j){
      const int c  = wid*4 + j;
      const int rc = c >> 1, h = c & 1;
      const size_t gcol = (size_t)(k0 + h*32 + gk*8);
      async_load16(A + (size_t)(mBase + rc*16 + sr)*K + gcol, &sA[c*512]);
    }
    #pragma unroll
    for (int j = 0; j < NWJ; ++j){
      const int c  = wid*NWJ + j;
      const int rc = c >> 1, h = c & 1;
      const size_t gcol = (size_t)(k0 + h*32 + gk*8);
      async_load16(Bt + (size_t)(nBase + rc*16 + sr)*K + gcol, &sB[c*512]);
    }
    __syncthreads();
    #pragma unroll
    for (int h = 0; h < 2; ++h){
      bf16x8 af[4], bfr[NWJ];
      #pragma unroll
      for (int i = 0; i < 4; ++i)
        af[i] = *(const bf16x8*)&sA[((wm*4 + i)*2 + h)*512 + rr*32 + rp*8];
      #pragma unroll
      for (int j = 0; j < NWJ; ++j)
        bfr[j] = *(const bf16x8*)&sB[((wn*NWJ + j)*2 + h)*512 + rr*32 + rp*8];
      #pragma unroll
      for (int i = 0; i < 4; ++i)
        #pragma unroll
        for (int j = 0; j < NWJ; ++j)
          acc[i][j] = __builtin_amdgcn_mfma_f32_16x16x32_bf16(af[i], bfr[j], acc[i][j], 0, 0, 0);
    }
  }

  const int rqd = (lane>>4)*4, cl = lane & 15;
  #pragma unroll
  for (int i = 0; i < 4; ++i){
    #pragma unroll
    for (int j = 0; j < NWJ; ++j){
      const int col = nBase + wn*(NWJ*16) + j*16 + cl;
      const float bv = (col < Nb) ? bias[col] : 0.0f;
      #pragma unroll
      for (int r = 0; r < 4; ++r){
        const int row = mBase + wm*64 + i*16 + rqd + r;
        const float v = acc[i][j][r] + bv;
        const size_t o = (size_t)row*N + col;
        if (EPI == 0)      ((uint16_t*)outp)[o] = f2bf(v);
        else if (EPI == 1) ((uint16_t*)outp)[o] = f2bf(gelu_fast(v));
        else               ((float*)outp)[o] = v + res[o];
      }
    }
  }
}

// ---------------- host launcher ----------------
extern "C" void kernel_launch(void* const* d_in, const int* in_sizes, int n_in,
                              void* d_out, int out_size, void* d_ws, size_t ws_size,
                              hipStream_t stream)
{
  const float* x      = (const float*)d_in[0];
  const float* cosb   = (const float*)d_in[1];
  const float* sinb   = (const float*)d_in[2];
  const float* qkv_w  = (const float*)d_in[4];
  const float* qkv_b  = (const float*)d_in[5];
  const float* proj_w = (const float*)d_in[6];
  const float* proj_b = (const float*)d_in[7];
  const float* ln1_w  = (const float*)d_in[8];
  const float* ln1_b  = (const float*)d_in[9];
  const float* ln2_w  = (const float*)d_in[10];
  const float* ln2_b  = (const float*)d_in[11];
  const float* fc1_w  = (const float*)d_in[12];
  const float* fc1_b  = (const float*)d_in[13];
  const float* fc2_w  = (const float*)d_in[14];
  const float* fc2_b  = (const float*)d_in[15];

  char* ws = (char*)d_ws;
  uint16_t* Wqkv  = (uint16_t*)(ws + 0);          // [3456][1152] bf16
  uint16_t* Wproj = (uint16_t*)(ws + 7962624);    // [1152][1152] bf16
  uint16_t* Wfc1  = (uint16_t*)(ws + 10616832);   // [4352][1152] bf16
  uint16_t* Wfc2  = (uint16_t*)(ws + 20643840);   // [1152][4352] bf16
  uint16_t* Hbuf  = (uint16_t*)(ws + 30670848);   // [16384][1152] bf16 (LN out / attn out)
  uint16_t* QKV   = (uint16_t*)(ws + 68419584);   // [16384][3456] bf16
  uint16_t* MB    = QKV;                          // [16384][4352] bf16 overlays QKV
  float* X1 = (float*)d_out;                      // fp32 [16384][1152], residual stream

  // prep: LN1 (blocks 0..4095) + all 4 weight transposes, one dispatch
  prep_kernel<<<19072, 256, 0, stream>>>(x, ln1_w, ln1_b, Hbuf,
                                         qkv_w, Wqkv, proj_w, Wproj,
                                         fc1_w, Wfc1, fc2_w, Wfc2);

  // QKV = Hbuf @ Wqkv^T + b -> bf16 (unrotated; RoPE inside attn). 36x96 n-tiles, 6 exact rounds.
  gemm_bt<0,3><<<36*128, 256, 0, stream>>>(Hbuf, Wqkv, qkv_b, QKVN, nullptr, QKV, QKVN, HID, 36);
  // MFMA windowed attention with fused RoPE -> Hbuf (bf16). 4 blk/CU, 4.0 exact rounds.
  attn_kernel<<<4096, 256, 0, stream>>>(QKV, cosb, sinb, Hbuf);
  // X1 = x + Hbuf @ Wproj^T + b  (fp32, into d_out). 12x96 n-tiles, 2 exact rounds.
  gemm_bt<2,3><<<12*128, 256, 0, stream>>>(Hbuf, Wproj, proj_b, HID, x, X1, HID, HID, 12);
  // LN2 -> Hbuf (bf16)
  ln_kernel<<<4096, 256, 0, stream>>>(X1, ln2_w, ln2_b, Hbuf);
  // MB = gelu(Hbuf @ Wfc1^T + b)  (bf16, padded N=4352: keeps MB K-pad zero for fc2)
  gemm_bt<1,4><<<34*128, 256, 0, stream>>>(Hbuf, Wfc1, fc1_b, INTER, nullptr, MB, INTERP, HID, 34);
  // out = X1 + MB @ Wfc2^T + b   (fp32, in-place on d_out). 12x96 n-tiles, 2 exact rounds.
  gemm_bt<2,3><<<12*128, 256, 0, stream>>>(MB, Wfc2, fc2_b, HID, X1, X1, HID, INTERP, 12);
}